// Round 6
// baseline (28.707 us; speedup 1.0000x reference)
//
#include <hip/hip_runtime.h>
#include <hip/hip_bf16.h>

typedef float v4f    __attribute__((ext_vector_type(4)));
typedef float f32x16 __attribute__((ext_vector_type(16)));
typedef __bf16 bf16x8 __attribute__((ext_vector_type(8)));

#define BATCH 4096
#define NF 26
#define NV 100000
#define ND_ 16      // embedding dim D (= MFMA K)
#define NA 16       // attention dim A
#define NDENSE 13
#define NPAIR 325   // NF*(NF-1)/2
#define ROWP 20     // padded LDS row stride in floats (80B)
#define WPB 4       // waves per block, 1 item per wave
#define BLOCK (WPB * 64)
#define NTILE 11    // pairs per column (32 cols x 11 = 352 >= 325)

__global__ __launch_bounds__(BLOCK) void afm_kernel(
    const float* __restrict__ dense,     // [B, 13]
    const int*   __restrict__ sparse,    // [B, 26]
    const float* __restrict__ tables,    // [26, 100000, 16]
    const float* __restrict__ attW,      // [16, 16] row-major [d][k]
    const float* __restrict__ attB,      // [16]
    const float* __restrict__ attH,      // [16]
    const float* __restrict__ attP,      // [16]
    const float* __restrict__ wDense,    // [13]
    const float* __restrict__ wSparse,   // [416]
    const float* __restrict__ linB,      // [1]
    float* __restrict__ out)             // [B]
{
    __shared__ __align__(16) float sEmb[WPB][NF * ROWP];

    const int tid  = threadIdx.x;
    const int wave = tid >> 6;
    const int lane = tid & 63;
    const int col  = lane & 31;   // MFMA column (pair slot)
    const int hi   = lane >> 5;   // K-half: supplies k = hi*8 .. hi*8+7
    const int b    = blockIdx.x * WPB + wave;

    // ---- sparse indices: direct load, broadcast via shfl (no LDS, no barrier)
    int idxreg = 0;
    if (lane < NF) idxreg = sparse[b * NF + lane];

    // ---- gather embeddings into wave-private padded LDS rows ----
    #pragma unroll
    for (int rnd = 0; rnd < 2; ++rnd) {
        const int c = lane + rnd * 64;
        if (c < (NF * ND_) / 4) {
            const int f  = c >> 2;
            const int d4 = (c & 3) << 2;
            const int row = __shfl(idxreg, f);
            const float4 v = *reinterpret_cast<const float4*>(
                tables + ((size_t)f * NV + (size_t)row) * ND_ + d4);
            *reinterpret_cast<float4*>(&sEmb[wave][f * ROWP + d4]) = v;
        }
    }

    // ---- A-fragment: rows 0..15 = W^T, row 16 = att_p (weights, load once) ----
    bf16x8 afrag;
    #pragma unroll
    for (int t = 0; t < 8; ++t) {
        float a = 0.f;
        if (col < NA)       a = attW[(hi * 8 + t) * NA + col];
        else if (col == NA) a = attP[hi * 8 + t];
        afrag[t] = (__bf16)a;
    }
    float  hreg[8];
    f32x16 cinit = {0.f,0.f,0.f,0.f,0.f,0.f,0.f,0.f,0.f,0.f,0.f,0.f,0.f,0.f,0.f,0.f};
    #pragma unroll
    for (int r = 0; r < 8; ++r) {
        const int k = (r & 3) + 8 * (r >> 2) + 4 * hi;
        hreg[r]  = attH[k];
        cinit[r] = attB[k];    // bias folded into MFMA C-input
    }

    // compile-time ordering: gather ds_writes complete (lgkmcnt) before reads
    __builtin_amdgcn_wave_barrier();

    const float* __restrict__ semb = sEmb[wave];

    // ---- linear term (fp32) ----
    float lin = 0.f;
    #pragma unroll
    for (int rnd = 0; rnd < 7; ++rnd) {
        const int e = lane + rnd * 64;
        if (e < NF * ND_)
            lin += semb[(e >> 4) * ROWP + (e & 15)] * wSparse[e];
    }
    if (lane < NDENSE)
        lin += dense[b * NDENSE + lane] * wDense[lane];

    // ---- column init: (i, j) for pair p0 = col*NTILE (clamped) ----
    int p0 = col * NTILE;
    if (p0 > NPAIR - 1) p0 = NPAIR - 1;
    int i = 0, rem = p0;
    while (rem >= NF - 1 - i) { rem -= NF - 1 - i; ++i; }
    int j = i + 1 + rem;

    // ---- MFMA tile loop: tile t = { pairs c*NTILE + t } ----
    float num = 0.f, den = 0.f;
    v4f ri0, ri1;
    bool need_ri = true;

    for (int t = 0; t < NTILE; ++t) {
        if (need_ri) {   // i changes <=2x per column: register-cached row i
            const float* ri = semb + i * ROWP + hi * 8;
            ri0 = *reinterpret_cast<const v4f*>(ri);
            ri1 = *reinterpret_cast<const v4f*>(ri + 4);
            need_ri = false;
        }
        const float* rj = semb + j * ROWP + hi * 8;
        const v4f y0 = *reinterpret_cast<const v4f*>(rj);
        const v4f y1 = *reinterpret_cast<const v4f*>(rj + 4);
        const v4f e0 = ri0 * y0;     // v_pk_mul_f32
        const v4f e1 = ri1 * y1;

        bf16x8 bfrag;                 // B[k=hi*8+t][col] = EWP[pair][d]
        bfrag[0] = (__bf16)e0[0]; bfrag[1] = (__bf16)e0[1];
        bfrag[2] = (__bf16)e0[2]; bfrag[3] = (__bf16)e0[3];
        bfrag[4] = (__bf16)e1[0]; bfrag[5] = (__bf16)e1[1];
        bfrag[6] = (__bf16)e1[2]; bfrag[7] = (__bf16)e1[3];

        const f32x16 acc =
            __builtin_amdgcn_mfma_f32_32x32x16_bf16(afrag, bfrag, cinit, 0, 0, 0);

        // score partial over this lane's 8 z-rows; dp sits in acc[8] (row 16, hi=0)
        float sp = 0.f;
        #pragma unroll
        for (int r = 0; r < 8; ++r)
            sp = fmaf(fmaxf(acc[r], 0.f), hreg[r], sp);
        const float sfull = sp + __shfl_xor(sp, 32);

        const bool valid = (col * NTILE + t < NPAIR) && (hi == 0);
        const float ev = valid ? __expf(sfull) : 0.f;  // scores O(1e-5): no max-sub needed
        num = fmaf(ev, acc[8], num);
        den += ev;

        // advance (i, j): uniform arithmetic, stays in-range past the end
        ++j;
        if (j >= NF) {
            if (i < NF - 2) { ++i; }
            j = i + 1;
            need_ri = true;
        }
    }

    // ---- wave-reduce num/den/lin, finalize ----
    #pragma unroll
    for (int o = 32; o; o >>= 1) {
        num += __shfl_xor(num, o);
        den += __shfl_xor(den, o);
        lin += __shfl_xor(lin, o);
    }
    if (lane == 0) {
        const float x = num / den + lin + linB[0];
        out[b] = 1.f / (1.f + __expf(-x));
    }
}

extern "C" void kernel_launch(void* const* d_in, const int* in_sizes, int n_in,
                              void* d_out, int out_size, void* d_ws, size_t ws_size,
                              hipStream_t stream) {
    const float* dense   = (const float*)d_in[0];
    const int*   sparse  = (const int*)d_in[1];
    const float* tables  = (const float*)d_in[2];
    const float* attW    = (const float*)d_in[3];
    const float* attB    = (const float*)d_in[4];
    const float* attH    = (const float*)d_in[5];
    const float* attP    = (const float*)d_in[6];
    const float* wDense  = (const float*)d_in[7];
    const float* wSparse = (const float*)d_in[8];
    const float* linB    = (const float*)d_in[9];
    float* out = (float*)d_out;

    const int grid = BATCH / WPB;  // 1024 blocks, 1 wave per batch item
    afm_kernel<<<grid, BLOCK, 0, stream>>>(
        dense, sparse, tables, attW, attB, attH, attP,
        wDense, wSparse, linB, out);
}

// Round 7
// 14.873 us; speedup vs baseline: 1.9302x; 1.9302x over previous
//
#include <hip/hip_runtime.h>
#include <hip/hip_bf16.h>

typedef float v2f    __attribute__((ext_vector_type(2)));
typedef float v4f    __attribute__((ext_vector_type(4)));
typedef float f32x16 __attribute__((ext_vector_type(16)));
typedef __bf16 bf16x8 __attribute__((ext_vector_type(8)));

#define BATCH 4096
#define NF 26
#define NV 100000
#define ND_ 16      // embedding dim D (= MFMA K)
#define NA 16       // attention dim A
#define NDENSE 13
#define NPAIR 325   // NF*(NF-1)/2
#define ROWP 20     // padded LDS row stride in floats (80B)
#define WPB 4       // waves per block, 1 item per wave
#define BLOCK (WPB * 64)
#define NTILE 11    // ceil(325/32) MFMA tiles per item

__global__ __launch_bounds__(BLOCK) void afm_kernel(
    const float* __restrict__ dense,     // [B, 13]
    const int*   __restrict__ sparse,    // [B, 26]
    const float* __restrict__ tables,    // [26, 100000, 16]
    const float* __restrict__ attW,      // [16, 16] row-major [d][k]
    const float* __restrict__ attB,      // [16]
    const float* __restrict__ attH,      // [16]
    const float* __restrict__ attP,      // [16]
    const float* __restrict__ wDense,    // [13]
    const float* __restrict__ wSparse,   // [416]
    const float* __restrict__ linB,      // [1]
    float* __restrict__ out)             // [B]
{
    __shared__ int sOFF[NPAIR];                       // (i*ROWP) | (j*ROWP)<<16
    __shared__ __align__(16) float sEmb[WPB][NF * ROWP];

    const int tid  = threadIdx.x;
    const int wave = tid >> 6;
    const int lane = tid & 63;
    const int col  = lane & 31;   // MFMA M/N index (pair slot within tile)
    const int hi   = lane >> 5;   // K-half: this lane supplies k = hi*8 .. hi*8+7
    const int b    = blockIdx.x * WPB + wave;

    // ---- sparse indices: direct load + shfl broadcast (no LDS round trip) ----
    int idxreg = 0;
    if (lane < NF) idxreg = sparse[b * NF + lane];

    // ---- gather embeddings FIRST (latency hides under sOFF build below) ----
    #pragma unroll
    for (int rnd = 0; rnd < 2; ++rnd) {
        const int c = lane + rnd * 64;
        if (c < (NF * ND_) / 4) {
            const int f  = c >> 2;
            const int d4 = (c & 3) << 2;
            const int row = __shfl(idxreg, f);
            const float4 v = *reinterpret_cast<const float4*>(
                tables + ((size_t)f * NV + (size_t)row) * ND_ + d4);
            *reinterpret_cast<float4*>(&sEmb[wave][f * ROWP + d4]) = v;
        }
    }

    // ---- pair offset table (block-shared, one-time) ----
    for (int p = tid; p < NPAIR; p += BLOCK) {
        int i = 0, rem = p;
        while (rem >= NF - 1 - i) { rem -= NF - 1 - i; ++i; }
        const int j = i + 1 + rem;
        sOFF[p] = (i * ROWP) | ((j * ROWP) << 16);
    }

    // ---- A-fragment: rows 0..15 = W^T (A[m][d] = W[d][m]), row 16 = att_p ----
    bf16x8 afrag;
    #pragma unroll
    for (int t = 0; t < 8; ++t) {
        float a = 0.f;
        if (col < NA)       a = attW[(hi * 8 + t) * NA + col];
        else if (col == NA) a = attP[hi * 8 + t];
        afrag[t] = (__bf16)a;
    }
    // per-lane post weights: acc reg r holds z-row k=(r&3)+8*(r>>2)+4*hi
    float  hreg[8];
    f32x16 cinit = {0.f,0.f,0.f,0.f,0.f,0.f,0.f,0.f,0.f,0.f,0.f,0.f,0.f,0.f,0.f,0.f};
    #pragma unroll
    for (int r = 0; r < 8; ++r) {
        const int k = (r & 3) + 8 * (r >> 2) + 4 * hi;
        hreg[r]  = attH[k];
        cinit[r] = attB[k];    // bias folded into MFMA C-input
    }

    __syncthreads();   // orders sOFF cross-wave AND drains gather ds_writes once

    const float* __restrict__ semb = sEmb[wave];

    // ---- linear term (fp32) ----
    float lin = 0.f;
    #pragma unroll
    for (int rnd = 0; rnd < 7; ++rnd) {
        const int e = lane + rnd * 64;
        if (e < NF * ND_)
            lin += semb[(e >> 4) * ROWP + (e & 15)] * wSparse[e];
    }
    if (lane < NDENSE)
        lin += dense[b * NDENSE + lane] * wDense[lane];

    // ---- MFMA tile loop: 32 pairs per tile, straight-line, fully unrolled ----
    float num = 0.f, den = 0.f;
    #pragma unroll
    for (int t = 0; t < NTILE; ++t) {
        const int p     = t * 32 + col;
        const bool valid = (p < NPAIR) && (hi == 0);
        const int pc    = (p < NPAIR) ? p : (NPAIR - 1);
        const int offs  = sOFF[pc];
        const float* ri = semb + (offs & 0xffff) + hi * 8;
        const float* rj = semb + (offs >> 16)    + hi * 8;

        const v4f x0 = *reinterpret_cast<const v4f*>(ri);
        const v4f x1 = *reinterpret_cast<const v4f*>(ri + 4);
        const v4f y0 = *reinterpret_cast<const v4f*>(rj);
        const v4f y1 = *reinterpret_cast<const v4f*>(rj + 4);
        const v4f e0 = x0 * y0;      // v_pk_mul_f32
        const v4f e1 = x1 * y1;

        bf16x8 bfrag;                 // B[k=hi*8+t][col] = EWP[pair][d]
        bfrag[0] = (__bf16)e0[0]; bfrag[1] = (__bf16)e0[1];
        bfrag[2] = (__bf16)e0[2]; bfrag[3] = (__bf16)e0[3];
        bfrag[4] = (__bf16)e1[0]; bfrag[5] = (__bf16)e1[1];
        bfrag[6] = (__bf16)e1[2]; bfrag[7] = (__bf16)e1[3];

        const f32x16 acc =
            __builtin_amdgcn_mfma_f32_32x32x16_bf16(afrag, bfrag, cinit, 0, 0, 0);

        // relu(z).h over this lane's 8 z-rows — packed v2f (v_pk_max/v_pk_fma)
        v2f sp2 = {0.f, 0.f};
        #pragma unroll
        for (int r = 0; r < 4; ++r) {
            v2f z;  z.x = acc[2 * r];  z.y = acc[2 * r + 1];
            v2f zr; zr.x = fmaxf(z.x, 0.f); zr.y = fmaxf(z.y, 0.f);
            v2f h;  h.x = hreg[2 * r]; h.y = hreg[2 * r + 1];
            sp2 = zr * h + sp2;
        }
        const float sp = sp2.x + sp2.y;
        const float sfull = sp + __shfl_xor(sp, 32);

        // scores are O(1e-5): exp without max-subtraction is exact-safe
        const float ev = valid ? __expf(sfull) : 0.f;
        num = fmaf(ev, acc[8], num);   // dp = row 16 of MFMA output (hi=0 lanes)
        den += ev;
    }

    // ---- wave-reduce num/den/lin, finalize ----
    #pragma unroll
    for (int o = 32; o; o >>= 1) {
        num += __shfl_xor(num, o);
        den += __shfl_xor(den, o);
        lin += __shfl_xor(lin, o);
    }
    if (lane == 0) {
        const float x = num / den + lin + linB[0];
        out[b] = 1.f / (1.f + __expf(-x));
    }
}

extern "C" void kernel_launch(void* const* d_in, const int* in_sizes, int n_in,
                              void* d_out, int out_size, void* d_ws, size_t ws_size,
                              hipStream_t stream) {
    const float* dense   = (const float*)d_in[0];
    const int*   sparse  = (const int*)d_in[1];
    const float* tables  = (const float*)d_in[2];
    const float* attW    = (const float*)d_in[3];
    const float* attB    = (const float*)d_in[4];
    const float* attH    = (const float*)d_in[5];
    const float* attP    = (const float*)d_in[6];
    const float* wDense  = (const float*)d_in[7];
    const float* wSparse = (const float*)d_in[8];
    const float* linB    = (const float*)d_in[9];
    float* out = (float*)d_out;

    const int grid = BATCH / WPB;  // 1024 blocks, 1 wave per batch item
    afm_kernel<<<grid, BLOCK, 0, stream>>>(
        dense, sparse, tables, attW, attB, attH, attP,
        wDense, wSparse, linB, out);
}